// Round 6
// baseline (129.361 us; speedup 1.0000x reference)
//
#include <hip/hip_runtime.h>
#include <hip/hip_bf16.h>

#define B_   64
#define N_   256
#define P_   12
#define D_   128
#define BN_  (B_*N_)      // 16384
#define EPSV 1e-5f

typedef float  f32x4  __attribute__((ext_vector_type(4)));
typedef __bf16 bf16x8 __attribute__((ext_vector_type(8)));
typedef __bf16 bf16x4 __attribute__((ext_vector_type(4)));

// module-scope scratch (fully rewritten every launch -> deterministic)
__device__ float  g_avg[768*256];       // [b*12+p][n]  mean over d
__device__ float  g_mx [768*256];       // [b*12+p][n]  max over d
__device__ float  g_h1 [1536*128];      // rows 0..767 avg-branch, 768..1535 max
__device__ float  g_pool[BN_*P_];       // [bn][p] = sig(avg)+sig(max)
__device__ float  g_k  [BN_*D_];        // [bn][d]  softmax(silu(BN(x·wk)))
__device__ __bf16 g_xbf[(size_t)BN_*P_*D_];  // x as bf16, [bn][p][d]

__device__ inline float sigm_(float x) { return 1.0f / (1.0f + __expf(-x)); }

__device__ inline float dot4_(float4 a, float4 b, float acc) {
  acc = fmaf(a.x, b.x, acc); acc = fmaf(a.y, b.y, acc);
  acc = fmaf(a.z, b.z, acc); acc = fmaf(a.w, b.w, acc);
  return acc;
}

// ---------------- K1: pool stats + k-softmax + bf16 x export ---------------
// one wave per (b,n); half-wave owns even/odd p rows; all loads coalesced.
// k1 is BW-bound (~100MB read) with VALU headroom, so the k-branch and the
// fp32->bf16 conversion live here, off k3's latency-critical chain.
__global__ __launch_bounds__(256) void k1_pool(const float* __restrict__ x,
                                               const float* __restrict__ wk,
                                               const float* __restrict__ kg,
                                               const float* __restrict__ kb,
                                               const float* __restrict__ krm,
                                               const float* __restrict__ krv) {
  int w = threadIdx.x >> 6, l = threadIdx.x & 63;
  int bn = blockIdx.x * 4 + w;
  const float* xp = x + (size_t)bn * (P_ * D_);
  __bf16* xbp = g_xbf + (size_t)bn * (P_ * D_);
  int half = l >> 5, lane32 = l & 31;
  float ksc = kg[0] * rsqrtf(krv[0] + EPSV);
  float kbs = kb[0] - krm[0] * ksc;
  float s6[6], m6[6];
  float kr0 = 0, kr1 = 0, kr2 = 0, kr3 = 0;
#pragma unroll
  for (int pp = 0; pp < 6; ++pp) {
    int p = pp * 2 + half;
    float4 v = *(const float4*)(xp + p * D_ + lane32 * 4);
    // bf16 export (coalesced 8B/lane)
    bf16x4 h;
    h[0] = (__bf16)v.x; h[1] = (__bf16)v.y; h[2] = (__bf16)v.z; h[3] = (__bf16)v.w;
    *(bf16x4*)(xbp + p * D_ + lane32 * 4) = h;
    // k_raw partial (this half's p rows)
    float wkp = wk[p];
    kr0 = fmaf(v.x, wkp, kr0); kr1 = fmaf(v.y, wkp, kr1);
    kr2 = fmaf(v.z, wkp, kr2); kr3 = fmaf(v.w, wkp, kr3);
    // mean/max stats
    float s = (v.x + v.y) + (v.z + v.w);
    float m = fmaxf(fmaxf(v.x, v.y), fmaxf(v.z, v.w));
#pragma unroll
    for (int off = 16; off; off >>= 1) {
      s += __shfl_xor(s, off);
      m = fmaxf(m, __shfl_xor(m, off));
    }
    s6[pp] = s * (1.0f / D_);
    m6[pp] = m;
  }
  // kr: sum even+odd halves -> both halves hold full k_raw for d=lane32*4..+3
  kr0 += __shfl_xor(kr0, 32); kr1 += __shfl_xor(kr1, 32);
  kr2 += __shfl_xor(kr2, 32); kr3 += __shfl_xor(kr3, 32);
  // BN(1ch) + SiLU
  float z0 = kr0 * ksc + kbs, z1 = kr1 * ksc + kbs;
  float z2 = kr2 * ksc + kbs, z3 = kr3 * ksc + kbs;
  z0 = z0 * sigm_(z0); z1 = z1 * sigm_(z1);
  z2 = z2 * sigm_(z2); z3 = z3 * sigm_(z3);
  // softmax over d=128 (32 lanes x 4)
  float mx = fmaxf(fmaxf(z0, z1), fmaxf(z2, z3));
#pragma unroll
  for (int off = 16; off; off >>= 1) mx = fmaxf(mx, __shfl_xor(mx, off));
  float e0 = __expf(z0 - mx), e1 = __expf(z1 - mx);
  float e2 = __expf(z2 - mx), e3 = __expf(z3 - mx);
  float es = (e0 + e1) + (e2 + e3);
#pragma unroll
  for (int off = 16; off; off >>= 1) es += __shfl_xor(es, off);
  float inv = 1.0f / es;
  if (half == 0) {
    float4 kk; kk.x = e0 * inv; kk.y = e1 * inv; kk.z = e2 * inv; kk.w = e3 * inv;
    *(float4*)(g_k + (size_t)bn * D_ + lane32 * 4) = kk;
  }
  if (lane32 == 0) {
    int b = bn >> 8, n = bn & 255;
#pragma unroll
    for (int pp = 0; pp < 6; ++pp) {
      int p = pp * 2 + half;
      g_avg[(b * P_ + p) * N_ + n] = s6[pp];
      g_mx [(b * P_ + p) * N_ + n] = m6[pp];
    }
  }
}

// ---------------- K2a: layer1 (256->128) + exact GELU -----------------------
__global__ __launch_bounds__(256) void k2_l1(const float* __restrict__ w_avg1,
                                             const float* __restrict__ w_max1) {
  __shared__ float in_t[16 * 256];
  __shared__ float w_t[64 * 68];
  int t = threadIdx.x;
  int rblk = blockIdx.x % 96, cblk = blockIdx.x / 96;
  int rr0 = rblk * 16, c0 = cblk * 64;
  bool mxb = (rr0 >= 768);
  int r768 = mxb ? rr0 - 768 : rr0;
  const float* in = (mxb ? g_mx : g_avg) + (size_t)r768 * 256;
  const float* w1 = mxb ? w_max1 : w_avg1;
#pragma unroll
  for (int i = 0; i < 4; ++i) {
    int F = t + i * 256, r = F >> 6, k4 = F & 63;
    *(float4*)(in_t + r * 256 + k4 * 4) = *(const float4*)(in + r * 256 + k4 * 4);
  }
  int c = t & 63, rq = t >> 6;
  float a0 = 0, a1 = 0, a2 = 0, a3 = 0;
  for (int kc = 0; kc < 4; ++kc) {
    __syncthreads();
#pragma unroll
    for (int i = 0; i < 4; ++i) {
      int F = t + i * 256, cr = F >> 4, k4 = F & 15;
      *(float4*)(w_t + cr * 68 + k4 * 4) =
          *(const float4*)(w1 + (size_t)(c0 + cr) * 256 + kc * 64 + k4 * 4);
    }
    __syncthreads();
#pragma unroll
    for (int k4 = 0; k4 < 16; ++k4) {
      float4 wv4 = *(float4*)(w_t + c * 68 + k4 * 4);
      a0 = dot4_(*(float4*)(in_t + (rq * 4 + 0) * 256 + kc * 64 + k4 * 4), wv4, a0);
      a1 = dot4_(*(float4*)(in_t + (rq * 4 + 1) * 256 + kc * 64 + k4 * 4), wv4, a1);
      a2 = dot4_(*(float4*)(in_t + (rq * 4 + 2) * 256 + kc * 64 + k4 * 4), wv4, a2);
      a3 = dot4_(*(float4*)(in_t + (rq * 4 + 3) * 256 + kc * 64 + k4 * 4), wv4, a3);
    }
  }
  float accs[4] = {a0, a1, a2, a3};
#pragma unroll
  for (int r = 0; r < 4; ++r) {
    float a = accs[r];
    float g = 0.5f * a * (1.0f + erff(a * 0.70710678f));
    g_h1[(size_t)(rr0 + rq * 4 + r) * 128 + c0 + c] = g;
  }
}

// ---------------- K2b: layer2 (128->256), sigmoid, branch-sum ---------------
__global__ __launch_bounds__(256) void k2_l2(const float* __restrict__ w_avg2,
                                             const float* __restrict__ w_max2) {
  __shared__ float ina_t[16 * 128];
  __shared__ float inm_t[16 * 128];
  __shared__ float wa_t[64 * 68];
  __shared__ float wm_t[64 * 68];
  int t = threadIdx.x;
  int rblk = blockIdx.x % 48, cblk = blockIdx.x / 48;
  int rr0 = rblk * 16, n0 = cblk * 64;
#pragma unroll
  for (int i = 0; i < 2; ++i) {
    int F = t + i * 256, r = F >> 5, k4 = F & 31;
    *(float4*)(ina_t + r * 128 + k4 * 4) = *(const float4*)(g_h1 + (size_t)(rr0 + r) * 128 + k4 * 4);
    *(float4*)(inm_t + r * 128 + k4 * 4) = *(const float4*)(g_h1 + (size_t)(768 + rr0 + r) * 128 + k4 * 4);
  }
  int c = t & 63, rq = t >> 6;
  float aa0=0, aa1=0, aa2=0, aa3=0, am0=0, am1=0, am2=0, am3=0;
  for (int kc = 0; kc < 2; ++kc) {
    __syncthreads();
#pragma unroll
    for (int i = 0; i < 4; ++i) {
      int F = t + i * 256, cr = F >> 4, k4 = F & 15;
      *(float4*)(wa_t + cr * 68 + k4 * 4) =
          *(const float4*)(w_avg2 + (size_t)(n0 + cr) * 128 + kc * 64 + k4 * 4);
      *(float4*)(wm_t + cr * 68 + k4 * 4) =
          *(const float4*)(w_max2 + (size_t)(n0 + cr) * 128 + kc * 64 + k4 * 4);
    }
    __syncthreads();
#pragma unroll
    for (int k4 = 0; k4 < 16; ++k4) {
      float4 wa4 = *(float4*)(wa_t + c * 68 + k4 * 4);
      float4 wm4 = *(float4*)(wm_t + c * 68 + k4 * 4);
      float4 i0 = *(float4*)(ina_t + (rq * 4 + 0) * 128 + kc * 64 + k4 * 4);
      float4 i1 = *(float4*)(ina_t + (rq * 4 + 1) * 128 + kc * 64 + k4 * 4);
      float4 i2 = *(float4*)(ina_t + (rq * 4 + 2) * 128 + kc * 64 + k4 * 4);
      float4 i3 = *(float4*)(ina_t + (rq * 4 + 3) * 128 + kc * 64 + k4 * 4);
      aa0 = dot4_(i0, wa4, aa0); aa1 = dot4_(i1, wa4, aa1);
      aa2 = dot4_(i2, wa4, aa2); aa3 = dot4_(i3, wa4, aa3);
      float4 j0 = *(float4*)(inm_t + (rq * 4 + 0) * 128 + kc * 64 + k4 * 4);
      float4 j1 = *(float4*)(inm_t + (rq * 4 + 1) * 128 + kc * 64 + k4 * 4);
      float4 j2 = *(float4*)(inm_t + (rq * 4 + 2) * 128 + kc * 64 + k4 * 4);
      float4 j3 = *(float4*)(inm_t + (rq * 4 + 3) * 128 + kc * 64 + k4 * 4);
      am0 = dot4_(j0, wm4, am0); am1 = dot4_(j1, wm4, am1);
      am2 = dot4_(j2, wm4, am2); am3 = dot4_(j3, wm4, am3);
    }
  }
  float va[4] = {aa0, aa1, aa2, aa3};
  float vm[4] = {am0, am1, am2, am3};
#pragma unroll
  for (int r = 0; r < 4; ++r) {
    int rr = rr0 + rq * 4 + r;
    int b = rr / 12, p = rr % 12;
    float pv = sigm_(va[r]) + sigm_(vm[r]);
    g_pool[((size_t)b * 256 + (n0 + c)) * 12 + p] = pv;
  }
}

// ---------------- K3: fused main, lean latency chain ------------------------
// grid = 2048 blocks x 256 thr; wave handles 2 bn. Inputs pre-digested by k1:
// A-frags load straight as bf16x8 (no cvt), k loads ready-made. No barriers
// in the loop. LDS ~36KB -> 4 blocks/CU. Plain launch_bounds (VGPR~128; the
// (256,4) variant forced 64 VGPR -> 250MB scratch spills in R2/R3).
__global__ __launch_bounds__(256) void k3_main(
    const float* __restrict__ wv,
    const float* __restrict__ vg, const float* __restrict__ vb,
    const float* __restrict__ vrm, const float* __restrict__ vrv,
    float* __restrict__ out) {
  __shared__ __align__(16) __bf16 wv_lds[128 * 128];  // [e][d] bf16, *sv[e], XOR-swizzled
  __shared__ float sv_l[128], tv_l[128];
  __shared__ float yp_l[4][128];      // per-wave y_pool redistribution
  __shared__ __align__(16) float y_l[4][16];  // per-wave y (12 used)

  int t = threadIdx.x, w = t >> 6, l = t & 63;
  if (t < 128) {
    float s = vg[t] * rsqrtf(vrv[t] + EPSV);
    sv_l[t] = s;
    tv_l[t] = vb[t] - vrm[t] * s;
  }
  __syncthreads();
  {
    int e = t >> 1, dh = (t & 1) * 64;
    float s = sv_l[e];
    int swz = (e & 7) << 4;
#pragma unroll
    for (int i = 0; i < 16; ++i) {
      float4 v4 = *(const float4*)(wv + (size_t)e * 128 + dh + i * 4);
      bf16x4 h;
      h[0] = (__bf16)(v4.x * s); h[1] = (__bf16)(v4.y * s);
      h[2] = (__bf16)(v4.z * s); h[3] = (__bf16)(v4.w * s);
      int byte = (e * 256 + (dh + i * 4) * 2) ^ swz;
      *(bf16x4*)((char*)wv_lds + byte) = h;
    }
  }
  __syncthreads();   // wv_lds ready; read-only from here on

  int arow = (l & 15) > 11 ? 11 : (l & 15);  // clamp pad rows
  int ak = (l >> 4) * 8;
  int bcol = l & 15;
  int bko = (l >> 4) * 16;
  int p0 = (l >> 4) * 4;                     // C rows owned by this lane
  bool rows_ok = (p0 < 12);

  float tv_e[8];
#pragma unroll
  for (int nt = 0; nt < 8; ++nt) tv_e[nt] = tv_l[bcol + nt * 16];

  for (int it = 0; it < 2; ++it) {
    int bn = blockIdx.x * 8 + it * 4 + w;

    // pool gates for this lane's 4 rows (0 for pad rows)
    float pool_r[4] = {0.f, 0.f, 0.f, 0.f};
    if (rows_ok) {
      const float* pp = g_pool + (size_t)bn * 12 + p0;
#pragma unroll
      for (int r = 0; r < 4; ++r) pool_r[r] = pp[r];
    }

    // k in MFMA column layout (precomputed by k1)
    const float* kp = g_k + (size_t)bn * D_;
    float k_e[8];
#pragma unroll
    for (int nt = 0; nt < 8; ++nt) k_e[nt] = kp[bcol + nt * 16];

    // A fragments: direct bf16x8 loads (converted by k1)
    const __bf16* xbp = g_xbf + (size_t)bn * (P_ * D_) + arow * D_;
    bf16x8 afr[4];
#pragma unroll
    for (int ks = 0; ks < 4; ++ks)
      afr[ks] = *(const bf16x8*)(xbp + ks * 32 + ak);

    // v_raw = xf @ (wv*sv)^T via MFMA 16x16x32 bf16
    f32x4 acc[8];
#pragma unroll
    for (int nt = 0; nt < 8; ++nt) acc[nt] = (f32x4){0.f, 0.f, 0.f, 0.f};
#pragma unroll
    for (int nt = 0; nt < 8; ++nt) {
      int er = bcol + nt * 16;
      int base = er * 256;
      int sw = (er & 7) << 4;
#pragma unroll
      for (int ks = 0; ks < 4; ++ks) {
        int byte = (base + ks * 64 + bko) ^ sw;
        bf16x8 bfr = *(const bf16x8*)((const char*)wv_lds + byte);
        acc[nt] = __builtin_amdgcn_mfma_f32_16x16x32_bf16(afr[ks], bfr, acc[nt], 0, 0, 0);
      }
    }

    // epilogue in registers: v = silu(v_raw + tv); y_r += v*k; ypp = pool.v
    float y_r[4] = {0.f, 0.f, 0.f, 0.f};
    float ypp[8];
#pragma unroll
    for (int nt = 0; nt < 8; ++nt) {
      float s = 0.f;
#pragma unroll
      for (int r = 0; r < 4; ++r) {
        float a = acc[nt][r] + tv_e[nt];
        float v = a * sigm_(a);
        y_r[r] = fmaf(v, k_e[nt], y_r[r]);
        s = fmaf(pool_r[r], v, s);
      }
      ypp[nt] = s;
    }
    // y[p]: reduce over 16 lanes of the column group
#pragma unroll
    for (int r = 0; r < 4; ++r) {
#pragma unroll
      for (int off = 8; off; off >>= 1) y_r[r] += __shfl_xor(y_r[r], off);
    }
    // y_pool[e]: reduce across the 4 row groups
#pragma unroll
    for (int nt = 0; nt < 8; ++nt) {
      ypp[nt] += __shfl_xor(ypp[nt], 16);
      ypp[nt] += __shfl_xor(ypp[nt], 32);
    }

    // redistribute y / y_pool via per-wave LDS for coalesced stores
    if (bcol == 0 && rows_ok) {
      float4 yq; yq.x = y_r[0]; yq.y = y_r[1]; yq.z = y_r[2]; yq.w = y_r[3];
      *(float4*)(&y_l[w][p0]) = yq;
    }
    if (l < 16) {
#pragma unroll
      for (int nt = 0; nt < 8; ++nt) yp_l[w][bcol + nt * 16] = ypp[nt];
    }
    // same-wave LDS write->read: compiler-inserted lgkmcnt wait suffices
    float2 yp2 = *(const float2*)(&yp_l[w][2 * l]);
    float yv[P_];
#pragma unroll
    for (int p = 0; p < P_; ++p) yv[p] = y_l[w][p];

    float* op = out + (size_t)bn * (P_ * D_);
#pragma unroll
    for (int p = 0; p < P_; ++p) {
      float2 o;
      o.x = yv[p] * yp2.x;
      o.y = yv[p] * yp2.y;
      *(float2*)(op + p * 128 + 2 * l) = o;
    }
  }
}

extern "C" void kernel_launch(void* const* d_in, const int* in_sizes, int n_in,
                              void* d_out, int out_size, void* d_ws, size_t ws_size,
                              hipStream_t stream) {
  const float* x   = (const float*)d_in[0];
  const float* wk  = (const float*)d_in[1];
  const float* kg  = (const float*)d_in[2];
  const float* kbb = (const float*)d_in[3];
  const float* krm = (const float*)d_in[4];
  const float* krv = (const float*)d_in[5];
  const float* wvp = (const float*)d_in[6];
  const float* vg  = (const float*)d_in[7];
  const float* vbb = (const float*)d_in[8];
  const float* vrm = (const float*)d_in[9];
  const float* vrv = (const float*)d_in[10];
  const float* wa1 = (const float*)d_in[11];
  const float* wa2 = (const float*)d_in[12];
  const float* wm1 = (const float*)d_in[13];
  const float* wm2 = (const float*)d_in[14];
  float* out = (float*)d_out;

  k1_pool<<<4096, 256, 0, stream>>>(x, wk, kg, kbb, krm, krv);
  k2_l1<<<192, 256, 0, stream>>>(wa1, wm1);
  k2_l2<<<192, 256, 0, stream>>>(wa2, wm2);
  k3_main<<<2048, 256, 0, stream>>>(wvp, vg, vbb, vrm, vrv, out);
}

// Round 7
// 118.586 us; speedup vs baseline: 1.0909x; 1.0909x over previous
//
#include <hip/hip_runtime.h>
#include <hip/hip_bf16.h>

#define B_   64
#define N_   256
#define P_   12
#define D_   128
#define BN_  (B_*N_)      // 16384
#define EPSV 1e-5f

typedef float  f32x4  __attribute__((ext_vector_type(4)));
typedef __bf16 bf16x8 __attribute__((ext_vector_type(8)));
typedef __bf16 bf16x4 __attribute__((ext_vector_type(4)));

// module-scope scratch (fully rewritten every launch -> deterministic)
__device__ float  g_avg[768*256];       // [b*12+p][n]  mean over d
__device__ float  g_mx [768*256];       // [b*12+p][n]  max over d
__device__ float  g_h1 [1536*128];      // rows 0..767 avg, 768..1535 max
__device__ float  g_pool[BN_*P_];       // [bn][p] = sig(avg)+sig(max)
__device__ float  g_k  [BN_*D_];        // [bn][d]  softmax(silu(BN(x·wk)))
__device__ __bf16 g_xbf[(size_t)BN_*P_*D_];       // x as bf16
__device__ __align__(16) __bf16 g_wvbf[128*128];  // wv*sv, bf16, pre-swizzled
__device__ float  g_tv [128];           // BN shift

__device__ inline float sigm_(float x) { return 1.0f / (1.0f + __expf(-x)); }

__device__ inline float dot4_(float4 a, float4 b, float acc) {
  acc = fmaf(a.x, b.x, acc); acc = fmaf(a.y, b.y, acc);
  acc = fmaf(a.z, b.z, acc); acc = fmaf(a.w, b.w, acc);
  return acc;
}

// ---------------- K0: pre-bake wv -> scaled bf16, XOR-swizzled layout -------
// g_wvbf[q] = value at (e = q>>8, d = (((q&255)^((e&7)<<4))>>1)) so k3 can
// stage with PURE 16B copies (linear LDS = swizzled layout). Also g_tv.
__global__ __launch_bounds__(256) void k0_prep(const float* __restrict__ wv,
                                               const float* __restrict__ vg,
                                               const float* __restrict__ vb,
                                               const float* __restrict__ vrm,
                                               const float* __restrict__ vrv) {
  int t = blockIdx.x * 256 + threadIdx.x;   // 4096 threads, 4 bf16 each
  if (blockIdx.x == 0 && threadIdx.x < 128) {
    float s0 = vg[threadIdx.x] * rsqrtf(vrv[threadIdx.x] + EPSV);
    g_tv[threadIdx.x] = vb[threadIdx.x] - vrm[threadIdx.x] * s0;
  }
  int e = t >> 5;                 // 32 threads per 256B row
  float s = vg[e] * rsqrtf(vrv[e] + EPSV);
  int qbase = t * 8;              // output byte offset (8B per thread)
  int swz = (e & 7) << 4;
  bf16x4 h;
#pragma unroll
  for (int j = 0; j < 4; ++j) {
    int inner = ((qbase & 255) + j * 2) ^ swz;
    h[j] = (__bf16)(wv[e * 128 + (inner >> 1)] * s);
  }
  *(bf16x4*)((char*)g_wvbf + qbase) = h;
}

// ---------------- K1: pool stats + k-softmax + bf16 x export ----------------
__global__ __launch_bounds__(256) void k1_pool(const float* __restrict__ x,
                                               const float* __restrict__ wk,
                                               const float* __restrict__ kg,
                                               const float* __restrict__ kb,
                                               const float* __restrict__ krm,
                                               const float* __restrict__ krv) {
  int w = threadIdx.x >> 6, l = threadIdx.x & 63;
  int bn = blockIdx.x * 4 + w;
  const float* xp = x + (size_t)bn * (P_ * D_);
  __bf16* xbp = g_xbf + (size_t)bn * (P_ * D_);
  int half = l >> 5, lane32 = l & 31;
  float ksc = kg[0] * rsqrtf(krv[0] + EPSV);
  float kbs = kb[0] - krm[0] * ksc;
  float s6[6], m6[6];
  float kr0 = 0, kr1 = 0, kr2 = 0, kr3 = 0;
#pragma unroll
  for (int pp = 0; pp < 6; ++pp) {
    int p = pp * 2 + half;
    float4 v = *(const float4*)(xp + p * D_ + lane32 * 4);
    bf16x4 h;
    h[0] = (__bf16)v.x; h[1] = (__bf16)v.y; h[2] = (__bf16)v.z; h[3] = (__bf16)v.w;
    *(bf16x4*)(xbp + p * D_ + lane32 * 4) = h;
    float wkp = wk[p];
    kr0 = fmaf(v.x, wkp, kr0); kr1 = fmaf(v.y, wkp, kr1);
    kr2 = fmaf(v.z, wkp, kr2); kr3 = fmaf(v.w, wkp, kr3);
    float s = (v.x + v.y) + (v.z + v.w);
    float m = fmaxf(fmaxf(v.x, v.y), fmaxf(v.z, v.w));
#pragma unroll
    for (int off = 16; off; off >>= 1) {
      s += __shfl_xor(s, off);
      m = fmaxf(m, __shfl_xor(m, off));
    }
    s6[pp] = s * (1.0f / D_);
    m6[pp] = m;
  }
  kr0 += __shfl_xor(kr0, 32); kr1 += __shfl_xor(kr1, 32);
  kr2 += __shfl_xor(kr2, 32); kr3 += __shfl_xor(kr3, 32);
  float z0 = kr0 * ksc + kbs, z1 = kr1 * ksc + kbs;
  float z2 = kr2 * ksc + kbs, z3 = kr3 * ksc + kbs;
  z0 = z0 * sigm_(z0); z1 = z1 * sigm_(z1);
  z2 = z2 * sigm_(z2); z3 = z3 * sigm_(z3);
  float mx = fmaxf(fmaxf(z0, z1), fmaxf(z2, z3));
#pragma unroll
  for (int off = 16; off; off >>= 1) mx = fmaxf(mx, __shfl_xor(mx, off));
  float e0 = __expf(z0 - mx), e1 = __expf(z1 - mx);
  float e2 = __expf(z2 - mx), e3 = __expf(z3 - mx);
  float es = (e0 + e1) + (e2 + e3);
#pragma unroll
  for (int off = 16; off; off >>= 1) es += __shfl_xor(es, off);
  float inv = 1.0f / es;
  if (half == 0) {
    float4 kk; kk.x = e0 * inv; kk.y = e1 * inv; kk.z = e2 * inv; kk.w = e3 * inv;
    *(float4*)(g_k + (size_t)bn * D_ + lane32 * 4) = kk;
  }
  if (lane32 == 0) {
    int b = bn >> 8, n = bn & 255;
#pragma unroll
    for (int pp = 0; pp < 6; ++pp) {
      int p = pp * 2 + half;
      g_avg[(b * P_ + p) * N_ + n] = s6[pp];
      g_mx [(b * P_ + p) * N_ + n] = m6[pp];
    }
  }
}

// ---------------- K2a: layer1 (256->128) + exact GELU -----------------------
__global__ __launch_bounds__(256) void k2_l1(const float* __restrict__ w_avg1,
                                             const float* __restrict__ w_max1) {
  __shared__ float in_t[16 * 256];
  __shared__ float w_t[64 * 68];
  int t = threadIdx.x;
  int rblk = blockIdx.x % 96, cblk = blockIdx.x / 96;
  int rr0 = rblk * 16, c0 = cblk * 64;
  bool mxb = (rr0 >= 768);
  int r768 = mxb ? rr0 - 768 : rr0;
  const float* in = (mxb ? g_mx : g_avg) + (size_t)r768 * 256;
  const float* w1 = mxb ? w_max1 : w_avg1;
#pragma unroll
  for (int i = 0; i < 4; ++i) {
    int F = t + i * 256, r = F >> 6, k4 = F & 63;
    *(float4*)(in_t + r * 256 + k4 * 4) = *(const float4*)(in + r * 256 + k4 * 4);
  }
  int c = t & 63, rq = t >> 6;
  float a0 = 0, a1 = 0, a2 = 0, a3 = 0;
  for (int kc = 0; kc < 4; ++kc) {
    __syncthreads();
#pragma unroll
    for (int i = 0; i < 4; ++i) {
      int F = t + i * 256, cr = F >> 4, k4 = F & 15;
      *(float4*)(w_t + cr * 68 + k4 * 4) =
          *(const float4*)(w1 + (size_t)(c0 + cr) * 256 + kc * 64 + k4 * 4);
    }
    __syncthreads();
#pragma unroll
    for (int k4 = 0; k4 < 16; ++k4) {
      float4 wv4 = *(float4*)(w_t + c * 68 + k4 * 4);
      a0 = dot4_(*(float4*)(in_t + (rq * 4 + 0) * 256 + kc * 64 + k4 * 4), wv4, a0);
      a1 = dot4_(*(float4*)(in_t + (rq * 4 + 1) * 256 + kc * 64 + k4 * 4), wv4, a1);
      a2 = dot4_(*(float4*)(in_t + (rq * 4 + 2) * 256 + kc * 64 + k4 * 4), wv4, a2);
      a3 = dot4_(*(float4*)(in_t + (rq * 4 + 3) * 256 + kc * 64 + k4 * 4), wv4, a3);
    }
  }
  float accs[4] = {a0, a1, a2, a3};
#pragma unroll
  for (int r = 0; r < 4; ++r) {
    float a = accs[r];
    float g = 0.5f * a * (1.0f + erff(a * 0.70710678f));
    g_h1[(size_t)(rr0 + rq * 4 + r) * 128 + c0 + c] = g;
  }
}

// ---------------- K2b: layer2 (128->256), sigmoid, branch-sum ---------------
__global__ __launch_bounds__(256) void k2_l2(const float* __restrict__ w_avg2,
                                             const float* __restrict__ w_max2) {
  __shared__ float ina_t[16 * 128];
  __shared__ float inm_t[16 * 128];
  __shared__ float wa_t[64 * 68];
  __shared__ float wm_t[64 * 68];
  int t = threadIdx.x;
  int rblk = blockIdx.x % 48, cblk = blockIdx.x / 48;
  int rr0 = rblk * 16, n0 = cblk * 64;
#pragma unroll
  for (int i = 0; i < 2; ++i) {
    int F = t + i * 256, r = F >> 5, k4 = F & 31;
    *(float4*)(ina_t + r * 128 + k4 * 4) = *(const float4*)(g_h1 + (size_t)(rr0 + r) * 128 + k4 * 4);
    *(float4*)(inm_t + r * 128 + k4 * 4) = *(const float4*)(g_h1 + (size_t)(768 + rr0 + r) * 128 + k4 * 4);
  }
  int c = t & 63, rq = t >> 6;
  float aa0=0, aa1=0, aa2=0, aa3=0, am0=0, am1=0, am2=0, am3=0;
  for (int kc = 0; kc < 2; ++kc) {
    __syncthreads();
#pragma unroll
    for (int i = 0; i < 4; ++i) {
      int F = t + i * 256, cr = F >> 4, k4 = F & 15;
      *(float4*)(wa_t + cr * 68 + k4 * 4) =
          *(const float4*)(w_avg2 + (size_t)(n0 + cr) * 128 + kc * 64 + k4 * 4);
      *(float4*)(wm_t + cr * 68 + k4 * 4) =
          *(const float4*)(w_max2 + (size_t)(n0 + cr) * 128 + kc * 64 + k4 * 4);
    }
    __syncthreads();
#pragma unroll
    for (int k4 = 0; k4 < 16; ++k4) {
      float4 wa4 = *(float4*)(wa_t + c * 68 + k4 * 4);
      float4 wm4 = *(float4*)(wm_t + c * 68 + k4 * 4);
      float4 i0 = *(float4*)(ina_t + (rq * 4 + 0) * 128 + kc * 64 + k4 * 4);
      float4 i1 = *(float4*)(ina_t + (rq * 4 + 1) * 128 + kc * 64 + k4 * 4);
      float4 i2 = *(float4*)(ina_t + (rq * 4 + 2) * 128 + kc * 64 + k4 * 4);
      float4 i3 = *(float4*)(ina_t + (rq * 4 + 3) * 128 + kc * 64 + k4 * 4);
      aa0 = dot4_(i0, wa4, aa0); aa1 = dot4_(i1, wa4, aa1);
      aa2 = dot4_(i2, wa4, aa2); aa3 = dot4_(i3, wa4, aa3);
      float4 j0 = *(float4*)(inm_t + (rq * 4 + 0) * 128 + kc * 64 + k4 * 4);
      float4 j1 = *(float4*)(inm_t + (rq * 4 + 1) * 128 + kc * 64 + k4 * 4);
      float4 j2 = *(float4*)(inm_t + (rq * 4 + 2) * 128 + kc * 64 + k4 * 4);
      float4 j3 = *(float4*)(inm_t + (rq * 4 + 3) * 128 + kc * 64 + k4 * 4);
      am0 = dot4_(j0, wm4, am0); am1 = dot4_(j1, wm4, am1);
      am2 = dot4_(j2, wm4, am2); am3 = dot4_(j3, wm4, am3);
    }
  }
  float va[4] = {aa0, aa1, aa2, aa3};
  float vm[4] = {am0, am1, am2, am3};
#pragma unroll
  for (int r = 0; r < 4; ++r) {
    int rr = rr0 + rq * 4 + r;
    int b = rr / 12, p = rr % 12;
    float pv = sigm_(va[r]) + sigm_(vm[r]);
    g_pool[((size_t)b * 256 + (n0 + c)) * 12 + p] = pv;
  }
}

// ---------------- K3: fused main, DUAL-bn waves -----------------------------
// grid = 1024 blocks x 256 thr; each wave processes 2 bn SIMULTANEOUSLY
// (twin register streams, shared B ds_reads), 2 dual-iterations = 4 bn/wave.
// Staging = pure 16B copies of pre-baked g_wvbf. No barriers in the loop.
// Plain launch_bounds: (256,4) forced 64 VGPR -> 250MB spills (R2/R3 lesson).
__global__ __launch_bounds__(256) void k3_main(float* __restrict__ out) {
  __shared__ __align__(16) __bf16 wv_lds[128 * 128];   // 32KB, pre-swizzled
  __shared__ float tv_l[128];
  __shared__ float yp_l[4][2][128];
  __shared__ __align__(16) float y_l[4][2][16];

  int t = threadIdx.x, w = t >> 6, l = t & 63;
  if (t < 128) tv_l[t] = g_tv[t];
  {
    const uint4* src = (const uint4*)g_wvbf;
    uint4* dst = (uint4*)wv_lds;
#pragma unroll
    for (int i = 0; i < 8; ++i) {
      int idx = i * 256 + t;
      dst[idx] = src[idx];
    }
  }
  __syncthreads();   // wv_lds ready; read-only from here on

  int arow = (l & 15) > 11 ? 11 : (l & 15);
  int ak = (l >> 4) * 8;
  int bcol = l & 15;
  int bko = (l >> 4) * 16;
  int p0 = (l >> 4) * 4;
  bool rows_ok = (p0 < 12);

  float tv_e[8];
#pragma unroll
  for (int nt = 0; nt < 8; ++nt) tv_e[nt] = tv_l[bcol + nt * 16];

  for (int it = 0; it < 2; ++it) {
    int bnA = blockIdx.x * 16 + it * 8 + w;
    int bnB = bnA + 4;

    // ---- loads for both bn (independent streams, deep in flight) ----
    const __bf16* xpA = g_xbf + (size_t)bnA * (P_ * D_) + arow * D_;
    const __bf16* xpB = g_xbf + (size_t)bnB * (P_ * D_) + arow * D_;
    bf16x8 afrA[4], afrB[4];
#pragma unroll
    for (int ks = 0; ks < 4; ++ks) {
      afrA[ks] = *(const bf16x8*)(xpA + ks * 32 + ak);
      afrB[ks] = *(const bf16x8*)(xpB + ks * 32 + ak);
    }
    const float* kpA = g_k + (size_t)bnA * D_;
    const float* kpB = g_k + (size_t)bnB * D_;
    float keA[8], keB[8];
#pragma unroll
    for (int nt = 0; nt < 8; ++nt) {
      keA[nt] = kpA[bcol + nt * 16];
      keB[nt] = kpB[bcol + nt * 16];
    }
    float poolA[4] = {0.f, 0.f, 0.f, 0.f};
    float poolB[4] = {0.f, 0.f, 0.f, 0.f};
    if (rows_ok) {
      const float* ppA = g_pool + (size_t)bnA * 12 + p0;
      const float* ppB = g_pool + (size_t)bnB * 12 + p0;
#pragma unroll
      for (int r = 0; r < 4; ++r) { poolA[r] = ppA[r]; poolB[r] = ppB[r]; }
    }

    // ---- MFMA + per-nt epilogue, twin streams share B fragments ----
    float yrA[4] = {0.f, 0.f, 0.f, 0.f};
    float yrB[4] = {0.f, 0.f, 0.f, 0.f};
    float yppA[8], yppB[8];
#pragma unroll
    for (int nt = 0; nt < 8; ++nt) {
      int er = bcol + nt * 16;
      int base = er * 256;
      int sw = (er & 7) << 4;
      f32x4 aA = (f32x4){0.f, 0.f, 0.f, 0.f};
      f32x4 aB = (f32x4){0.f, 0.f, 0.f, 0.f};
#pragma unroll
      for (int ks = 0; ks < 4; ++ks) {
        int byte = (base + ks * 64 + bko) ^ sw;
        bf16x8 bfr = *(const bf16x8*)((const char*)wv_lds + byte);
        aA = __builtin_amdgcn_mfma_f32_16x16x32_bf16(afrA[ks], bfr, aA, 0, 0, 0);
        aB = __builtin_amdgcn_mfma_f32_16x16x32_bf16(afrB[ks], bfr, aB, 0, 0, 0);
      }
      float tvv = tv_e[nt];
      float sA = 0.f, sB = 0.f;
#pragma unroll
      for (int r = 0; r < 4; ++r) {
        float a = aA[r] + tvv;
        float v = a * sigm_(a);
        yrA[r] = fmaf(v, keA[nt], yrA[r]);
        sA = fmaf(poolA[r], v, sA);
        float b = aB[r] + tvv;
        float vb2 = b * sigm_(b);
        yrB[r] = fmaf(vb2, keB[nt], yrB[r]);
        sB = fmaf(poolB[r], vb2, sB);
      }
      yppA[nt] = sA; yppB[nt] = sB;
    }

    // ---- reduces (twin chains interleave) ----
#pragma unroll
    for (int r = 0; r < 4; ++r) {
#pragma unroll
      for (int off = 8; off; off >>= 1) {
        yrA[r] += __shfl_xor(yrA[r], off);
        yrB[r] += __shfl_xor(yrB[r], off);
      }
    }
#pragma unroll
    for (int nt = 0; nt < 8; ++nt) {
      yppA[nt] += __shfl_xor(yppA[nt], 16);
      yppA[nt] += __shfl_xor(yppA[nt], 32);
      yppB[nt] += __shfl_xor(yppB[nt], 16);
      yppB[nt] += __shfl_xor(yppB[nt], 32);
    }

    // ---- redistribute via per-wave LDS; coalesced float2 row stores ----
    if (bcol == 0 && rows_ok) {
      float4 qA; qA.x = yrA[0]; qA.y = yrA[1]; qA.z = yrA[2]; qA.w = yrA[3];
      float4 qB; qB.x = yrB[0]; qB.y = yrB[1]; qB.z = yrB[2]; qB.w = yrB[3];
      *(float4*)(&y_l[w][0][p0]) = qA;
      *(float4*)(&y_l[w][1][p0]) = qB;
    }
    if (l < 16) {
#pragma unroll
      for (int nt = 0; nt < 8; ++nt) {
        yp_l[w][0][bcol + nt * 16] = yppA[nt];
        yp_l[w][1][bcol + nt * 16] = yppB[nt];
      }
    }
    // same-wave LDS write->read: compiler-inserted lgkmcnt wait suffices
    float2 ypA = *(const float2*)(&yp_l[w][0][2 * l]);
    float2 ypB = *(const float2*)(&yp_l[w][1][2 * l]);
    float* opA = out + (size_t)bnA * (P_ * D_);
    float* opB = out + (size_t)bnB * (P_ * D_);
#pragma unroll
    for (int p = 0; p < P_; ++p) {
      float yvA = y_l[w][0][p];
      float2 oA; oA.x = yvA * ypA.x; oA.y = yvA * ypA.y;
      *(float2*)(opA + p * 128 + 2 * l) = oA;
      float yvB = y_l[w][1][p];
      float2 oB; oB.x = yvB * ypB.x; oB.y = yvB * ypB.y;
      *(float2*)(opB + p * 128 + 2 * l) = oB;
    }
  }
}

extern "C" void kernel_launch(void* const* d_in, const int* in_sizes, int n_in,
                              void* d_out, int out_size, void* d_ws, size_t ws_size,
                              hipStream_t stream) {
  const float* x   = (const float*)d_in[0];
  const float* wk  = (const float*)d_in[1];
  const float* kg  = (const float*)d_in[2];
  const float* kbb = (const float*)d_in[3];
  const float* krm = (const float*)d_in[4];
  const float* krv = (const float*)d_in[5];
  const float* wvp = (const float*)d_in[6];
  const float* vg  = (const float*)d_in[7];
  const float* vbb = (const float*)d_in[8];
  const float* vrm = (const float*)d_in[9];
  const float* vrv = (const float*)d_in[10];
  const float* wa1 = (const float*)d_in[11];
  const float* wa2 = (const float*)d_in[12];
  const float* wm1 = (const float*)d_in[13];
  const float* wm2 = (const float*)d_in[14];
  float* out = (float*)d_out;

  k0_prep<<<16, 256, 0, stream>>>(wvp, vg, vbb, vrm, vrv);
  k1_pool<<<4096, 256, 0, stream>>>(x, wk, kg, kbb, krm, krv);
  k2_l1<<<192, 256, 0, stream>>>(wa1, wm1);
  k2_l2<<<192, 256, 0, stream>>>(wa2, wm2);
  k3_main<<<1024, 256, 0, stream>>>(out);
}

// Round 9
// 111.004 us; speedup vs baseline: 1.1654x; 1.0683x over previous
//
#include <hip/hip_runtime.h>
#include <hip/hip_bf16.h>

#define B_   64
#define N_   256
#define P_   12
#define D_   128
#define BN_  (B_*N_)      // 16384
#define EPSV 1e-5f

typedef float  f32x4  __attribute__((ext_vector_type(4)));
typedef __bf16 bf16x8 __attribute__((ext_vector_type(8)));
typedef __bf16 bf16x4 __attribute__((ext_vector_type(4)));

// module-scope scratch (fully rewritten every launch -> deterministic)
__device__ float  g_avg[768*256];       // [b*12+p][n]  mean over d
__device__ float  g_mx [768*256];       // [b*12+p][n]  max over d
__device__ float  g_h1 [1536*128];      // rows 0..767 avg, 768..1535 max
__device__ float  g_pool[BN_*P_];       // [bn][p] = sig(avg)+sig(max)
__device__ float  g_k  [BN_*D_];        // [bn][d]  softmax(silu(BN(x·wk)))
__device__ __bf16 g_xbf[(size_t)BN_*P_*D_];       // x as bf16
__device__ __align__(16) __bf16 g_wvbf[128*128];  // wv*sv, bf16, LINEAR [e][d]
__device__ float  g_tv [128];           // BN shift

__device__ inline float sigm_(float x) { return 1.0f / (1.0f + __expf(-x)); }

__device__ inline float dot4_(float4 a, float4 b, float acc) {
  acc = fmaf(a.x, b.x, acc); acc = fmaf(a.y, b.y, acc);
  acc = fmaf(a.z, b.z, acc); acc = fmaf(a.w, b.w, acc);
  return acc;
}

// ---------------- K0: pre-bake wv -> scaled bf16 (linear) + g_tv ------------
__global__ __launch_bounds__(256) void k0_prep(const float* __restrict__ wv,
                                               const float* __restrict__ vg,
                                               const float* __restrict__ vb,
                                               const float* __restrict__ vrm,
                                               const float* __restrict__ vrv) {
  int t = blockIdx.x * 256 + threadIdx.x;   // 4096 threads, 4 bf16 each
  if (blockIdx.x == 0 && threadIdx.x < 128) {
    float s0 = vg[threadIdx.x] * rsqrtf(vrv[threadIdx.x] + EPSV);
    g_tv[threadIdx.x] = vb[threadIdx.x] - vrm[threadIdx.x] * s0;
  }
  int idx = t * 4;
  int e = idx >> 7, d0 = idx & 127;
  float s = vg[e] * rsqrtf(vrv[e] + EPSV);
  bf16x4 h;
#pragma unroll
  for (int j = 0; j < 4; ++j) h[j] = (__bf16)(wv[e * 128 + d0 + j] * s);
  *(bf16x4*)(g_wvbf + idx) = h;
}

// ---------------- K1: pool stats + k-softmax + bf16 x export ----------------
__global__ __launch_bounds__(256) void k1_pool(const float* __restrict__ x,
                                               const float* __restrict__ wk,
                                               const float* __restrict__ kg,
                                               const float* __restrict__ kb,
                                               const float* __restrict__ krm,
                                               const float* __restrict__ krv) {
  int w = threadIdx.x >> 6, l = threadIdx.x & 63;
  int bn = blockIdx.x * 4 + w;
  const float* xp = x + (size_t)bn * (P_ * D_);
  __bf16* xbp = g_xbf + (size_t)bn * (P_ * D_);
  int half = l >> 5, lane32 = l & 31;
  float ksc = kg[0] * rsqrtf(krv[0] + EPSV);
  float kbs = kb[0] - krm[0] * ksc;
  float s6[6], m6[6];
  float kr0 = 0, kr1 = 0, kr2 = 0, kr3 = 0;
#pragma unroll
  for (int pp = 0; pp < 6; ++pp) {
    int p = pp * 2 + half;
    float4 v = *(const float4*)(xp + p * D_ + lane32 * 4);
    bf16x4 h;
    h[0] = (__bf16)v.x; h[1] = (__bf16)v.y; h[2] = (__bf16)v.z; h[3] = (__bf16)v.w;
    *(bf16x4*)(xbp + p * D_ + lane32 * 4) = h;
    float wkp = wk[p];
    kr0 = fmaf(v.x, wkp, kr0); kr1 = fmaf(v.y, wkp, kr1);
    kr2 = fmaf(v.z, wkp, kr2); kr3 = fmaf(v.w, wkp, kr3);
    float s = (v.x + v.y) + (v.z + v.w);
    float m = fmaxf(fmaxf(v.x, v.y), fmaxf(v.z, v.w));
#pragma unroll
    for (int off = 16; off; off >>= 1) {
      s += __shfl_xor(s, off);
      m = fmaxf(m, __shfl_xor(m, off));
    }
    s6[pp] = s * (1.0f / D_);
    m6[pp] = m;
  }
  kr0 += __shfl_xor(kr0, 32); kr1 += __shfl_xor(kr1, 32);
  kr2 += __shfl_xor(kr2, 32); kr3 += __shfl_xor(kr3, 32);
  float z0 = kr0 * ksc + kbs, z1 = kr1 * ksc + kbs;
  float z2 = kr2 * ksc + kbs, z3 = kr3 * ksc + kbs;
  z0 = z0 * sigm_(z0); z1 = z1 * sigm_(z1);
  z2 = z2 * sigm_(z2); z3 = z3 * sigm_(z3);
  float mx = fmaxf(fmaxf(z0, z1), fmaxf(z2, z3));
#pragma unroll
  for (int off = 16; off; off >>= 1) mx = fmaxf(mx, __shfl_xor(mx, off));
  float e0 = __expf(z0 - mx), e1 = __expf(z1 - mx);
  float e2 = __expf(z2 - mx), e3 = __expf(z3 - mx);
  float es = (e0 + e1) + (e2 + e3);
#pragma unroll
  for (int off = 16; off; off >>= 1) es += __shfl_xor(es, off);
  float inv = 1.0f / es;
  if (half == 0) {
    float4 kk; kk.x = e0 * inv; kk.y = e1 * inv; kk.z = e2 * inv; kk.w = e3 * inv;
    *(float4*)(g_k + (size_t)bn * D_ + lane32 * 4) = kk;
  }
  if (lane32 == 0) {
    int b = bn >> 8, n = bn & 255;
#pragma unroll
    for (int pp = 0; pp < 6; ++pp) {
      int p = pp * 2 + half;
      g_avg[(b * P_ + p) * N_ + n] = s6[pp];
      g_mx [(b * P_ + p) * N_ + n] = m6[pp];
    }
  }
}

// ---------------- K2a: layer1 (256->128) + exact GELU -----------------------
__global__ __launch_bounds__(256) void k2_l1(const float* __restrict__ w_avg1,
                                             const float* __restrict__ w_max1) {
  __shared__ float in_t[16 * 256];
  __shared__ float w_t[64 * 68];
  int t = threadIdx.x;
  int rblk = blockIdx.x % 96, cblk = blockIdx.x / 96;
  int rr0 = rblk * 16, c0 = cblk * 64;
  bool mxb = (rr0 >= 768);
  int r768 = mxb ? rr0 - 768 : rr0;
  const float* in = (mxb ? g_mx : g_avg) + (size_t)r768 * 256;
  const float* w1 = mxb ? w_max1 : w_avg1;
#pragma unroll
  for (int i = 0; i < 4; ++i) {
    int F = t + i * 256, r = F >> 6, k4 = F & 63;
    *(float4*)(in_t + r * 256 + k4 * 4) = *(const float4*)(in + r * 256 + k4 * 4);
  }
  int c = t & 63, rq = t >> 6;
  float a0 = 0, a1 = 0, a2 = 0, a3 = 0;
  for (int kc = 0; kc < 4; ++kc) {
    __syncthreads();
#pragma unroll
    for (int i = 0; i < 4; ++i) {
      int F = t + i * 256, cr = F >> 4, k4 = F & 15;
      *(float4*)(w_t + cr * 68 + k4 * 4) =
          *(const float4*)(w1 + (size_t)(c0 + cr) * 256 + kc * 64 + k4 * 4);
    }
    __syncthreads();
#pragma unroll
    for (int k4 = 0; k4 < 16; ++k4) {
      float4 wv4 = *(float4*)(w_t + c * 68 + k4 * 4);
      a0 = dot4_(*(float4*)(in_t + (rq * 4 + 0) * 256 + kc * 64 + k4 * 4), wv4, a0);
      a1 = dot4_(*(float4*)(in_t + (rq * 4 + 1) * 256 + kc * 64 + k4 * 4), wv4, a1);
      a2 = dot4_(*(float4*)(in_t + (rq * 4 + 2) * 256 + kc * 64 + k4 * 4), wv4, a2);
      a3 = dot4_(*(float4*)(in_t + (rq * 4 + 3) * 256 + kc * 64 + k4 * 4), wv4, a3);
    }
  }
  float accs[4] = {a0, a1, a2, a3};
#pragma unroll
  for (int r = 0; r < 4; ++r) {
    float a = accs[r];
    float g = 0.5f * a * (1.0f + erff(a * 0.70710678f));
    g_h1[(size_t)(rr0 + rq * 4 + r) * 128 + c0 + c] = g;
  }
}

// ---------------- K2b: layer2 (128->256), sigmoid, branch-sum ---------------
__global__ __launch_bounds__(256) void k2_l2(const float* __restrict__ w_avg2,
                                             const float* __restrict__ w_max2) {
  __shared__ float ina_t[16 * 128];
  __shared__ float inm_t[16 * 128];
  __shared__ float wa_t[64 * 68];
  __shared__ float wm_t[64 * 68];
  int t = threadIdx.x;
  int rblk = blockIdx.x % 48, cblk = blockIdx.x / 48;
  int rr0 = rblk * 16, n0 = cblk * 64;
#pragma unroll
  for (int i = 0; i < 2; ++i) {
    int F = t + i * 256, r = F >> 5, k4 = F & 31;
    *(float4*)(ina_t + r * 128 + k4 * 4) = *(const float4*)(g_h1 + (size_t)(rr0 + r) * 128 + k4 * 4);
    *(float4*)(inm_t + r * 128 + k4 * 4) = *(const float4*)(g_h1 + (size_t)(768 + rr0 + r) * 128 + k4 * 4);
  }
  int c = t & 63, rq = t >> 6;
  float aa0=0, aa1=0, aa2=0, aa3=0, am0=0, am1=0, am2=0, am3=0;
  for (int kc = 0; kc < 2; ++kc) {
    __syncthreads();
#pragma unroll
    for (int i = 0; i < 4; ++i) {
      int F = t + i * 256, cr = F >> 4, k4 = F & 15;
      *(float4*)(wa_t + cr * 68 + k4 * 4) =
          *(const float4*)(w_avg2 + (size_t)(n0 + cr) * 128 + kc * 64 + k4 * 4);
      *(float4*)(wm_t + cr * 68 + k4 * 4) =
          *(const float4*)(w_max2 + (size_t)(n0 + cr) * 128 + kc * 64 + k4 * 4);
    }
    __syncthreads();
#pragma unroll
    for (int k4 = 0; k4 < 16; ++k4) {
      float4 wa4 = *(float4*)(wa_t + c * 68 + k4 * 4);
      float4 wm4 = *(float4*)(wm_t + c * 68 + k4 * 4);
      float4 i0 = *(float4*)(ina_t + (rq * 4 + 0) * 128 + kc * 64 + k4 * 4);
      float4 i1 = *(float4*)(ina_t + (rq * 4 + 1) * 128 + kc * 64 + k4 * 4);
      float4 i2 = *(float4*)(ina_t + (rq * 4 + 2) * 128 + kc * 64 + k4 * 4);
      float4 i3 = *(float4*)(ina_t + (rq * 4 + 3) * 128 + kc * 64 + k4 * 4);
      aa0 = dot4_(i0, wa4, aa0); aa1 = dot4_(i1, wa4, aa1);
      aa2 = dot4_(i2, wa4, aa2); aa3 = dot4_(i3, wa4, aa3);
      float4 j0 = *(float4*)(inm_t + (rq * 4 + 0) * 128 + kc * 64 + k4 * 4);
      float4 j1 = *(float4*)(inm_t + (rq * 4 + 1) * 128 + kc * 64 + k4 * 4);
      float4 j2 = *(float4*)(inm_t + (rq * 4 + 2) * 128 + kc * 64 + k4 * 4);
      float4 j3 = *(float4*)(inm_t + (rq * 4 + 3) * 128 + kc * 64 + k4 * 4);
      am0 = dot4_(j0, wm4, am0); am1 = dot4_(j1, wm4, am1);
      am2 = dot4_(j2, wm4, am2); am3 = dot4_(j3, wm4, am3);
    }
  }
  float va[4] = {aa0, aa1, aa2, aa3};
  float vm[4] = {am0, am1, am2, am3};
#pragma unroll
  for (int r = 0; r < 4; ++r) {
    int rr = rr0 + rq * 4 + r;
    int b = rr / 12, p = rr % 12;
    float pv = sigm_(va[r]) + sigm_(vm[r]);
    g_pool[((size_t)b * 256 + (n0 + c)) * 12 + p] = pv;
  }
}

// ---------------- K3: fused main — register-resident B, zero LDS ------------
// grid = 4096 blocks x 64 thr; each wave loops 4 bn. KEY: wv' is constant
// across ALL bn -> each wave loads its 32 B-fragments ONCE into registers
// (128 VGPR) and reuses them; per-bn work is 4 A-loads + 32 MFMA + epilogue.
// No __shared__ at all: epilogue uses shfl broadcasts/selects only. This
// avoids R7's two unproven patterns (per-MFMA B-from-global interleave;
// single-wave LDS epilogue without barrier).
__global__ __launch_bounds__(64) void k3_main(float* __restrict__ out) {
  int l = threadIdx.x;
  int bcol = l & 15;
  int arow = bcol > 11 ? 11 : bcol;          // clamp pad rows
  int ak = (l >> 4) * 8;
  int p0 = (l >> 4) * 4;
  bool rows_ok = (p0 < 12);

  // one-time loads: B fragments + BN shift (bn-invariant)
  bf16x8 bfr[8][4];
#pragma unroll
  for (int nt = 0; nt < 8; ++nt) {
    const __bf16* wp = g_wvbf + (bcol + nt * 16) * 128 + ak;
#pragma unroll
    for (int ks = 0; ks < 4; ++ks)
      bfr[nt][ks] = *(const bf16x8*)(wp + ks * 32);
  }
  float tv_e[8];
#pragma unroll
  for (int nt = 0; nt < 8; ++nt) tv_e[nt] = g_tv[bcol + nt * 16];

  for (int it = 0; it < 4; ++it) {
    int bn = blockIdx.x * 4 + it;

    // per-bn loads: A fragments (proven global->MFMA path), k, pool
    const __bf16* xp = g_xbf + (size_t)bn * (P_ * D_) + arow * D_;
    bf16x8 afr[4];
#pragma unroll
    for (int ks = 0; ks < 4; ++ks) afr[ks] = *(const bf16x8*)(xp + ks * 32 + ak);
    const float* kp = g_k + (size_t)bn * D_;
    float k_e[8];
#pragma unroll
    for (int nt = 0; nt < 8; ++nt) k_e[nt] = kp[bcol + nt * 16];
    float pool_r[4] = {0.f, 0.f, 0.f, 0.f};
    if (rows_ok) {
      const float* pp = g_pool + (size_t)bn * 12 + p0;
#pragma unroll
      for (int r = 0; r < 4; ++r) pool_r[r] = pp[r];
    }

    // MFMA + rolling epilogue (all register operands except A)
    float y_r[4] = {0.f, 0.f, 0.f, 0.f};
    float ypp[8];
#pragma unroll
    for (int nt = 0; nt < 8; ++nt) {
      f32x4 acc = (f32x4){0.f, 0.f, 0.f, 0.f};
#pragma unroll
      for (int ks = 0; ks < 4; ++ks)
        acc = __builtin_amdgcn_mfma_f32_16x16x32_bf16(afr[ks], bfr[nt][ks], acc, 0, 0, 0);
      float tvv = tv_e[nt];
      float s = 0.f;
#pragma unroll
      for (int r = 0; r < 4; ++r) {
        float a = acc[r] + tvv;
        float v = a * sigm_(a);
        y_r[r] = fmaf(v, k_e[nt], y_r[r]);
        s = fmaf(pool_r[r], v, s);
      }
      ypp[nt] = s;
    }

    // reduces: y over the 16-lane column group; y_pool across 4 row groups
#pragma unroll
    for (int r = 0; r < 4; ++r) {
#pragma unroll
      for (int off = 8; off; off >>= 1) y_r[r] += __shfl_xor(y_r[r], off);
    }
#pragma unroll
    for (int nt = 0; nt < 8; ++nt) {
      ypp[nt] += __shfl_xor(ypp[nt], 16);
      ypp[nt] += __shfl_xor(ypp[nt], 32);
    }

    // gather this lane's two output columns e=2l,2l+1 (both in nt = l>>3):
    // source lane (e&15) in group 0 holds ypool[e] in ypp[e>>4].
    int cs = (l & 7) * 2;
    int ntw = l >> 3;
    float ypx = 0.f, ypy = 0.f;
#pragma unroll
    for (int nt = 0; nt < 8; ++nt) {
      float sx = __shfl(ypp[nt], cs);
      float sy = __shfl(ypp[nt], cs + 1);
      ypx = (ntw == nt) ? sx : ypx;
      ypy = (ntw == nt) ? sy : ypy;
    }

    // y[p] broadcast from lane (p>>2)*16 (holds full group sum); store rows
    float* op = out + (size_t)bn * (P_ * D_);
#pragma unroll
    for (int p = 0; p < P_; ++p) {
      float yp = __shfl(y_r[p & 3], (p >> 2) * 16);
      float2 o;
      o.x = yp * ypx;
      o.y = yp * ypy;
      *(float2*)(op + p * 128 + 2 * l) = o;
    }
  }
}

extern "C" void kernel_launch(void* const* d_in, const int* in_sizes, int n_in,
                              void* d_out, int out_size, void* d_ws, size_t ws_size,
                              hipStream_t stream) {
  const float* x   = (const float*)d_in[0];
  const float* wk  = (const float*)d_in[1];
  const float* kg  = (const float*)d_in[2];
  const float* kbb = (const float*)d_in[3];
  const float* krm = (const float*)d_in[4];
  const float* krv = (const float*)d_in[5];
  const float* wvp = (const float*)d_in[6];
  const float* vg  = (const float*)d_in[7];
  const float* vbb = (const float*)d_in[8];
  const float* vrm = (const float*)d_in[9];
  const float* vrv = (const float*)d_in[10];
  const float* wa1 = (const float*)d_in[11];
  const float* wa2 = (const float*)d_in[12];
  const float* wm1 = (const float*)d_in[13];
  const float* wm2 = (const float*)d_in[14];
  float* out = (float*)d_out;

  k0_prep<<<16, 256, 0, stream>>>(wvp, vg, vbb, vrm, vrv);
  k1_pool<<<4096, 256, 0, stream>>>(x, wk, kg, kbb, krm, krv);
  k2_l1<<<192, 256, 0, stream>>>(wa1, wm1);
  k2_l2<<<192, 256, 0, stream>>>(wa2, wm2);
  k3_main<<<4096, 64, 0, stream>>>(out);
}